// Round 8
// baseline (3560.195 us; speedup 1.0000x reference)
//
#include <hip/hip_runtime.h>
#include <hip/hip_fp16.h>

typedef _Float16 f16;
typedef _Float16 f16x2 __attribute__((ext_vector_type(2)));
typedef _Float16 f16x8 __attribute__((ext_vector_type(8)));
typedef float f32x4 __attribute__((ext_vector_type(4)));

__device__ __forceinline__ float fdot2v(f16x2 a, f16x2 b, float c){
#if __has_builtin(__builtin_amdgcn_fdot2)
  return __builtin_amdgcn_fdot2(a, b, c, false);
#else
  return c + (float)a.x * (float)b.x + (float)a.y * (float)b.y;
#endif
}

__device__ __forceinline__ float rcp_f(float x){
#if __has_builtin(__builtin_amdgcn_rcpf)
  return __builtin_amdgcn_rcpf(x);
#else
  return 1.f / x;
#endif
}

__device__ __forceinline__ float tanh_f(float x){
  return 1.f - 2.f * rcp_f(__expf(2.f * x) + 1.f);
}
__device__ __forceinline__ float sigm_f(float x){
  return rcp_f(1.f + __expf(-x));
}
__device__ __forceinline__ float leaky_f(float x){
  return x >= 0.f ? x : x * (1.0f / 5.5f);
}

// Load NP f32 pairs from row-major W[row][c0 + 2p (+1)] into f16x2 regs,
// zero-padding out-of-range columns. Row forced safe by caller when !valid.
template<int NP>
__device__ __forceinline__ void ld_pairs(const float* W, int row, int ncols, int c0,
                                         f16x2* dst, bool valid){
  const float* base = W + (long)row * ncols;
#pragma unroll
  for (int p = 0; p < NP; p++){
    int c = c0 + 2 * p;
    f16x2 v;
    v.x = (valid && c     < ncols) ? (f16)base[c]     : (f16)0.f;
    v.y = (valid && c + 1 < ncols) ? (f16)base[c + 1] : (f16)0.f;
    dst[p] = v;
  }
}

// Dot of NCH f16x8 LDS chunks against register weights w[4*NCH] (f16x2).
template<int NCH>
__device__ __forceinline__ float dot_chunks(const f16x2* w, const f16x8* x, int chunk0){
  float a0 = 0.f, a1 = 0.f, a2 = 0.f, a3 = 0.f;
#pragma unroll
  for (int c = 0; c < NCH; c++){
    union { f16x8 v; f16x2 h[4]; } u;
    u.v = x[chunk0 + c];
    a0 = fdot2v(w[4*c + 0], u.h[0], a0);
    a1 = fdot2v(w[4*c + 1], u.h[1], a1);
    a2 = fdot2v(w[4*c + 2], u.h[2], a2);
    a3 = fdot2v(w[4*c + 3], u.h[3], a3);
  }
  return (a0 + a1) + (a2 + a3);
}

// Build one MFMA A-fragment: 8 f16 along K for this lane's row.
// 16x16x32_f16 layout: row m = lane&15, k = 8*(lane>>4) + j (j = 0..7).
__device__ __forceinline__ f16x8 ldfrag(const float* W, int row, int ncols, int k0, bool valid){
  f16x8 v;
#pragma unroll
  for (int j = 0; j < 8; j++){
    int c = k0 + j;
    v[j] = (valid && c < ncols) ? (f16)W[(long)row * ncols + c] : (f16)0.f;
  }
  return v;
}

__device__ __forceinline__ float sel4(f32x4 a, int c){
  float v = a.x;
  v = (c == 1) ? a.y : v;
  v = (c == 2) ? a.z : v;
  v = (c == 3) ? a.w : v;
  return v;
}

#define MFMA16(A,B,C) __builtin_amdgcn_mfma_f32_16x16x32_f16((A),(B),(C),0,0,0)

// Field MLP as MFMA, 18 tiles of 16 rows for stages 1/2 (N=275 padded to 288;
// rows >=275 produce finite garbage multiplied by zero-padded weights downstream).
// Wave wv owns tiles {2wv, 2wv+1}; waves 6,7 additionally own tiles 16,17
// (rows 256..287) via the af[] overlay. Stage 3 (N=100): waves 0..5 own tiles
// 0..5 (rows 0..95) via af[]; rows 96..99 are a 16-way fdot2 tail on wave 7.
// Stage-1 input u: u[0]=0 (t applied as fp32 scalar), u[1+i]=y[i], padded to 128.
struct FRM {
  f16x8 a1[2][4];   // fW1 fragments, K = 128
  f16x8 a2[2][9];   // fW2 fragments, K = 288
  f16x8 af[13];     // wv<6: [0..8] = fW3 frags; wv>=6: [0..3] = fW1 tile16/17, [4..12] = fW2 tile16/17
  f16x2 w3b[9];     // wave 7: stage-3 tail rows 96..99, cols 18*lm..18*lm+17
  float w1tw, b1w, b2w;   // writer-lane (lm<12) consts
  float b3w;
};

// Decoder register context (k_forecast only; DCE'd when unused).
struct DEC {
  f16x2 dW1[16]; f16x2 dW2[12]; f16x2 dW3;
  float ob1v, ob2v, ob3v;
};

__device__ __forceinline__ void load_field_mfma(FRM& R, int tid,
    const float* fW1, const float* fb1, const float* fW2, const float* fb2,
    const float* fW3, const float* fb3)
{
  const int lane = tid & 63, wv = tid >> 6;
  const int lm = lane & 15, lg = lane >> 4;
  const int r0 = 32 * wv + lm, r1 = r0 + 16;      // rows of tiles 2wv, 2wv+1 (<= 255)
#pragma unroll
  for (int c = 0; c < 4; c++){
    R.a1[0][c] = ldfrag(fW1, r0, 101, 32 * c + 8 * lg, true);
    R.a1[1][c] = ldfrag(fW1, r1, 101, 32 * c + 8 * lg, true);
  }
#pragma unroll
  for (int c = 0; c < 9; c++){
    R.a2[0][c] = ldfrag(fW2, r0, 275, 32 * c + 8 * lg, true);
    R.a2[1][c] = ldfrag(fW2, r1, 275, 32 * c + 8 * lg, true);
  }
  if (wv < 6){
    const int r3 = 16 * wv + lm;                  // <= 95, always valid
#pragma unroll
    for (int c = 0; c < 9; c++)
      R.af[c] = ldfrag(fW3, r3, 275, 32 * c + 8 * lg, true);
#pragma unroll
    for (int c = 9; c < 13; c++) R.af[c] = (f16x8)(f16)0.f;
  } else {
    const int r2 = 256 + 16 * (wv - 6) + lm;      // tiles 16/17: rows 256..287
    const bool v2 = r2 < 275;
    const int r2c = v2 ? r2 : 0;
#pragma unroll
    for (int c = 0; c < 4; c++)
      R.af[c] = ldfrag(fW1, r2c, 101, 32 * c + 8 * lg, v2);
#pragma unroll
    for (int c = 0; c < 9; c++)
      R.af[4 + c] = ldfrag(fW2, r2c, 275, 32 * c + 8 * lg, v2);
  }
  // wave-7 stage-3 tail: rows 96+lg, 16-way K split over cols 18*lm..
  {
    const bool w7 = (wv == 7);
    ld_pairs<9>(fW3, w7 ? (96 + lg) : 0, 275, 18 * lm, R.w3b, w7);
  }
  // writer-lane consts (lm<12): s = lm>>2 selects tile {2wv, 2wv+1, extra}
  {
    const int s = lm >> 2;
    const bool use3 = (s == 2) && (wv >= 6);
    int rw = use3 ? (256 + 16 * (wv - 6) + 4 * lg + (lm & 3))
                  : (32 * wv + 16 * (s & 1) + 4 * lg + (lm & 3));
    int rwc = rw < 275 ? rw : 274;
    R.w1tw = fW1[rwc * 101];
    R.b1w  = fb1[rwc];
    R.b2w  = fb2[rwc];
  }
  if (wv < 6)       R.b3w = fb3[16 * wv + 4 * lg + (lm & 3)];   // rows <96
  else if (wv == 7) R.b3w = fb3[96 + lg];
  else              R.b3w = 0.f;
}

// One field evaluation via MFMA. ust: 128 f16 [0, y0..y99, 0...].
// x1s/x2s: 288 f16. 2 internal barriers. Returns stage-3 result:
// waves 0..5: f32x4 acc (rows 16wv+4lg+reg); wave 7: reduced tail value in .x
// (rows 96+lg on lm==0 lanes). Caller applies tanh + b3w on writer lanes.
// D=true folds one decoder evaluation (yv -> o1 -> o2 -> outl[tf], LDS);
// out-stage runs on wave 6 (idle in stage 3).
template<bool D>
__device__ __forceinline__ f32x4 field_eval_m(const FRM& R, const DEC& dc,
    float t, int tid, f16* ust, f16* x1s, f16* x2s,
    const f16x8* yv, f16* o1s, f16* o2s, float* outl, int tf)
{
  const int lm = tid & 15, lg = (tid >> 4) & 3, wv = tid >> 6;
  const bool x3 = (wv >= 6);
  const int nw = x3 ? 12 : 8;
  const f16x8* ub  = (const f16x8*)ust;
  const f16x8* x1b = (const f16x8*)x1s;
  const f16x8* x2b = (const f16x8*)x2s;
  const f32x4 zz = {0.f, 0.f, 0.f, 0.f};

  // ---- stage 1: x1 = tanh([t,y] @ fW1^T + fb1), 18 tiles MFMA ----
  {
    f16x8 u0 = ub[lg], u1 = ub[4 + lg], u2 = ub[8 + lg], u3 = ub[12 + lg];
    f32x4 A0 = zz, A1 = zz, A2 = zz, B0 = zz, B1 = zz, B2 = zz;
    __builtin_amdgcn_s_setprio(1);
    A0 = MFMA16(R.a1[0][0], u0, A0);  A1 = MFMA16(R.a1[1][0], u0, A1);
    B0 = MFMA16(R.a1[0][1], u1, B0);  B1 = MFMA16(R.a1[1][1], u1, B1);
    A0 = MFMA16(R.a1[0][2], u2, A0);  A1 = MFMA16(R.a1[1][2], u2, A1);
    B0 = MFMA16(R.a1[0][3], u3, B0);  B1 = MFMA16(R.a1[1][3], u3, B1);
    if (x3){
      A2 = MFMA16(R.af[0], u0, A2);  B2 = MFMA16(R.af[1], u1, B2);
      A2 = MFMA16(R.af[2], u2, A2);  B2 = MFMA16(R.af[3], u3, B2);
    }
    __builtin_amdgcn_s_setprio(0);
    if (D){                              // decoder stage 1 rides along
      int jq = tid >> 2, qq = tid & 3;
      if (jq < 75){
        float a = dot_chunks<4>(dc.dW1, yv, 4 * qq);
        a += __shfl_xor(a, 1); a += __shfl_xor(a, 2);
        if (qq == 0) o1s[jq] = (f16)leaky_f(a + dc.ob1v);
      }
    }
    if (lm < nw){
      int s = lm >> 2, reg = lm & 3;
      int rw = (s == 2) ? (256 + 16 * (wv - 6) + 4 * lg + reg)
                        : (32 * wv + 16 * s + 4 * lg + reg);
      float v0 = sel4(A0 + B0, reg), v1 = sel4(A1 + B1, reg), v2 = sel4(A2 + B2, reg);
      float v = (s == 0) ? v0 : ((s == 1) ? v1 : v2);
      x1s[rw] = (f16)tanh_f(v + R.w1tw * t + R.b1w);
    }
  }
  __syncthreads();

  // ---- stage 2: x2 = tanh(x1 @ fW2^T + fb2), 18 tiles MFMA ----
  {
    f32x4 A0 = zz, A1 = zz, A2 = zz, B0 = zz, B1 = zz, B2 = zz;
    __builtin_amdgcn_s_setprio(1);
#pragma unroll
    for (int c = 0; c < 5; c++){
      f16x8 bp = x1b[4 * c + lg];
      A0 = MFMA16(R.a2[0][c], bp, A0);
      A1 = MFMA16(R.a2[1][c], bp, A1);
      if (x3) A2 = MFMA16(R.af[4 + c], bp, A2);
    }
#pragma unroll
    for (int c = 5; c < 9; c++){
      f16x8 bq = x1b[4 * c + lg];
      B0 = MFMA16(R.a2[0][c], bq, B0);
      B1 = MFMA16(R.a2[1][c], bq, B1);
      if (x3) B2 = MFMA16(R.af[4 + c], bq, B2);
    }
    __builtin_amdgcn_s_setprio(0);
    if (D){                              // decoder stage 2
      int jq = tid >> 2, qq = tid & 3;
      if (jq < 75){
        float a = dot_chunks<3>(dc.dW2, (const f16x8*)o1s, 3 * qq);
        a += __shfl_xor(a, 1); a += __shfl_xor(a, 2);
        if (qq == 0) o2s[jq] = (f16)leaky_f(a + dc.ob2v);
      }
    }
    if (lm < nw){
      int s = lm >> 2, reg = lm & 3;
      int rw = (s == 2) ? (256 + 16 * (wv - 6) + 4 * lg + reg)
                        : (32 * wv + 16 * s + 4 * lg + reg);
      float v0 = sel4(A0 + B0, reg), v1 = sel4(A1 + B1, reg), v2 = sel4(A2 + B2, reg);
      float v = (s == 0) ? v0 : ((s == 1) ? v1 : v2);
      x2s[rw] = (f16)tanh_f(v + R.b2w);
    }
  }
  __syncthreads();

  // ---- stage 3: f = tanh(x2 @ fW3^T + fb3) ----
  f32x4 acc3 = zz;
  if (wv < 6){                           // rows 0..95 via MFMA
    f32x4 r0 = zz, r1 = zz;
    __builtin_amdgcn_s_setprio(1);
#pragma unroll
    for (int c = 0; c < 5; c++) r0 = MFMA16(R.af[c], x2b[4 * c + lg], r0);
#pragma unroll
    for (int c = 5; c < 9; c++) r1 = MFMA16(R.af[c], x2b[4 * c + lg], r1);
    __builtin_amdgcn_s_setprio(0);
    acc3 = r0 + r1;
  } else if (wv == 7){                   // rows 96..99, 16-way fdot2 tail
    float a2t = 0.f;
    const f16x2* xv2 = (const f16x2*)x2s + 9 * lm;
#pragma unroll
    for (int p = 0; p < 9; p++) a2t = fdot2v(R.w3b[p], xv2[p], a2t);
    a2t += __shfl_xor(a2t, 1); a2t += __shfl_xor(a2t, 2);
    a2t += __shfl_xor(a2t, 4); a2t += __shfl_xor(a2t, 8);
    acc3.x = a2t;
  }
  if (D){                                // decoder out-stage on wave 6 (LDS buffer)
    if (wv == 6){
      int t2 = tid - 384;
      float a = 0.f;
      if (t2 < 40) a = fdot2v(dc.dW3, ((const f16x2*)o2s)[t2], 0.f);
      a += __shfl_xor(a, 1);  a += __shfl_xor(a, 2);  a += __shfl_xor(a, 4);
      a += __shfl_xor(a, 8);  a += __shfl_xor(a, 16); a += __shfl_xor(a, 32);
      if (t2 == 0) outl[tf] = a + dc.ob3v;
    }
  }
  return acc3;
}

// ===================== Kernel 1: encoder + latent MLP =====================
__global__ __launch_bounds__(512, 2) void k_encode(
    const float* __restrict__ past, const float* __restrict__ h0,
    const float* __restrict__ fW1, const float* __restrict__ fb1,
    const float* __restrict__ fW2, const float* __restrict__ fb2,
    const float* __restrict__ fW3, const float* __restrict__ fb3,
    const float* __restrict__ Wih, const float* __restrict__ Whh,
    const float* __restrict__ bih, const float* __restrict__ bhh,
    const float* __restrict__ gW1, const float* __restrict__ gb1,
    const float* __restrict__ gW2, const float* __restrict__ gb2,
    const float* __restrict__ gW3, const float* __restrict__ gb3,
    float* __restrict__ gx_ws)
{
  __shared__ f16x8 ustV[16];     // [0, y, 0..] staged for stage-1 MFMA
  __shared__ f16x8 ystV[16];     // y-only staged (GRU / latent MLP)
  __shared__ f16x8 x1V[36];      // 288 f16
  __shared__ f16x8 x2V[36];
  __shared__ float yf[100];      // fp32 master state
  __shared__ float ghs[300];
  __shared__ float prow_lds[64]; // past row: VMEM-free main loop
  __shared__ f16x2 gW1s[75 * 52];
  __shared__ f16x2 gW2s[75 * 40];
  __shared__ f16x2 gW3s[80];
  __shared__ f16x2 g1s2[40];
  __shared__ f16x2 g2s2[40];

  const int tid = threadIdx.x;
  const int b = blockIdx.x;
  f16* ust = (f16*)ustV;
  f16* yst = (f16*)ystV;
  f16* x1s = (f16*)x1V;
  f16* x2s = (f16*)x2V;
  f16* g1s = (f16*)g1s2;
  f16* g2s = (f16*)g2s2;

  FRM R;
  load_field_mfma(R, tid, fW1, fb1, fW2, fb2, fW3, fb3);
  DEC dcz{};   // unused (D=false); DCE'd

  // GRU hidden-hidden: pass1 rows 0..255 (2-way chunked), pass2 rows 256..299 (8-way)
  f16x2 whh[28]; float bhhv;
  f16x2 whhb[7]; float bhhbv;
  {
    int j1 = tid >> 1, h = tid & 1;
    ld_pairs<28>(Whh, j1, 100, 56 * h, whh, true);
    bhhv = bhh[j1];
    bool p2 = tid < 352;
    int j2 = 256 + (tid >> 3), s7 = tid & 7;
    ld_pairs<7>(Whh, p2 ? j2 : 0, 100, 14 * s7, whhb, p2);
    bhhbv = p2 ? bhh[j2] : 0.f;
  }
  float wihr=0,wihz=0,wihn=0,bihr=0,bihz=0,bihn=0;
  if (tid < 100){
    wihr = Wih[tid];       bihr = bih[tid];
    wihz = Wih[tid + 100]; bihz = bih[tid + 100];
    wihn = Wih[tid + 200]; bihn = bih[tid + 200];
  }
  const int jq = tid >> 2, qq = tid & 3;
  const bool lv = (qq == 0 && jq < 75);
  float gb1v = lv ? gb1[jq] : 0.f;
  float gb2v = lv ? gb2[jq] : 0.f;

  // latent weights -> LDS (f16, padded strides; used once)
  for (int i = tid; i < 75 * 52; i += 512){
    int r = i / 52, c = 2 * (i % 52);
    f16x2 v;
    v.x = (c     < 100) ? (f16)gW1[r * 100 + c]     : (f16)0.f;
    v.y = (c + 1 < 100) ? (f16)gW1[r * 100 + c + 1] : (f16)0.f;
    gW1s[i] = v;
  }
  for (int i = tid; i < 75 * 40; i += 512){
    int r = i / 40, c = 2 * (i % 40);
    f16x2 v;
    v.x = (c     < 75) ? (f16)gW2[r * 75 + c]     : (f16)0.f;
    v.y = (c + 1 < 75) ? (f16)gW2[r * 75 + c + 1] : (f16)0.f;
    gW2s[i] = v;
  }
  for (int i = tid; i < 80; i += 512){
    int r = i / 40, c = 2 * (i % 40);
    f16x2 v;
    v.x = (c     < 75) ? (f16)gW3[r * 75 + c]     : (f16)0.f;
    v.y = (c + 1 < 75) ? (f16)gW3[r * 75 + c + 1] : (f16)0.f;
    gW3s[i] = v;
  }
  // staging init (ust[0] stays 0 forever; ust pads 101..127 stay 0)
  for (int i = tid; i < 128; i += 512){ ust[i] = (f16)0.f; yst[i] = (f16)0.f; }
  for (int i = tid; i < 288; i += 512){ x1s[i] = (f16)0.f; x2s[i] = (f16)0.f; }
  for (int i = tid; i < 80;  i += 512){ g1s[i] = (f16)0.f; g2s[i] = (f16)0.f; }
  if (tid < 64) prow_lds[tid] = past[b * 64 + tid];
  if (tid < 100){
    float v = h0[b * 100 + tid];
    yf[tid] = v; yst[tid] = (f16)v; ust[1 + tid] = (f16)v;
  }
  __syncthreads();

  const int lm = tid & 15, lg2 = (tid >> 4) & 3, wv = tid >> 6;
  bool wr3; int row3;
  if (wv < 6)      { wr3 = (lm < 4);  row3 = 16 * wv + 4 * lg2 + (lm & 3); }
  else if (wv == 7){ wr3 = (lm == 0); row3 = 96 + lg2; }
  else             { wr3 = false;     row3 = 0; }
  float k1v = 0.f, k2v = 0.f, k3v = 0.f;

  auto kval = [&](f32x4 a){
    float av = (wv == 7) ? a.x : sel4(a, lm);
    return tanh_f(av + R.b3w);
  };

  auto rk_interval = [&](float tp, float tc){
    float dts = (tc - tp) * 0.5f;   // (t1-t0)/NSUB
#pragma unroll 1
    for (int sub = 0; sub < 2; sub++){
      float t0 = tp + sub * dts;
      float yfr = 0.f;
      __syncthreads();
      if (wr3) yfr = yf[row3];       // refresh after GRU / previous substep
      f32x4 a = field_eval_m<false>(R, dcz, t0, tid, ust, x1s, x2s,
                                    nullptr, nullptr, nullptr, nullptr, 0);
      if (wr3){ float kv = kval(a); k1v = kv;
                ust[1 + row3] = (f16)(yfr + 0.5f * dts * kv); }
      __syncthreads();
      a = field_eval_m<false>(R, dcz, t0 + 0.5f * dts, tid, ust, x1s, x2s,
                              nullptr, nullptr, nullptr, nullptr, 0);
      if (wr3){ float kv = kval(a); k2v = kv;
                ust[1 + row3] = (f16)(yfr + 0.5f * dts * kv); }
      __syncthreads();
      a = field_eval_m<false>(R, dcz, t0 + 0.5f * dts, tid, ust, x1s, x2s,
                              nullptr, nullptr, nullptr, nullptr, 0);
      if (wr3){ float kv = kval(a); k3v = kv;
                ust[1 + row3] = (f16)(yfr + dts * kv); }
      __syncthreads();
      a = field_eval_m<false>(R, dcz, t0 + dts, tid, ust, x1s, x2s,
                              nullptr, nullptr, nullptr, nullptr, 0);
      if (wr3){
        float kv = kval(a);
        float yn = yfr + dts * (k1v + 2.f * (k2v + k3v) + kv) * (1.f / 6.f);
        yf[row3] = yn; ust[1 + row3] = (f16)yn; yst[row3] = (f16)yn;
      }
    }
  };

  float tprev = 0.f;
#pragma unroll 1
  for (int st = 0; st < 32; st++){
    float tc = prow_lds[2 * st];
    float tp = (st == 0) ? (tc - 1.f) : tprev;
    tprev = tc;
    rk_interval(tp, tc);
    // ---- GRU update ----
    __syncthreads();   // yst = integrated h ready
    {
      int j1 = tid >> 1, h = tid & 1;
      float a = dot_chunks<7>(whh, ystV, 7 * h);
      a += __shfl_xor(a, 1);
      if (!h) ghs[j1] = a + bhhv;
      if (tid < 352){
        int s7 = tid & 7;
        float a2 = 0.f;
        const f16x2* yv2 = (const f16x2*)ystV + 7 * s7;
#pragma unroll
        for (int p = 0; p < 7; p++) a2 = fdot2v(whhb[p], yv2[p], a2);
        a2 += __shfl_xor(a2, 1); a2 += __shfl_xor(a2, 2); a2 += __shfl_xor(a2, 4);
        if (s7 == 0) ghs[256 + (tid >> 3)] = a2 + bhhbv;
      }
    }
    __syncthreads();
    if (tid < 100){
      float x = prow_lds[2 * st + 1];
      float r = sigm_f(x * wihr + bihr + ghs[tid]);
      float z = sigm_f(x * wihz + bihz + ghs[tid + 100]);
      float n = tanh_f(x * wihn + bihn + r * ghs[tid + 200]);
      float hn = (1.f - z) * n + z * yf[tid];
      yf[tid] = hn; yst[tid] = (f16)hn; ust[1 + tid] = (f16)hn;
    }
  }

  // ---- latent MLP: gx = (leaky,leaky,linear)(h) ----
  __syncthreads();
  {
    float a = 0.f;
    const f16x2* yv = (const f16x2*)ystV + 13 * qq;
    if (jq < 75){
#pragma unroll
      for (int p = 0; p < 13; p++) a = fdot2v(gW1s[jq * 52 + 13 * qq + p], yv[p], a);
    }
    a += __shfl_xor(a, 1); a += __shfl_xor(a, 2);
    if (lv) g1s[jq] = (f16)leaky_f(a + gb1v);
  }
  __syncthreads();
  {
    float a = 0.f;
    const f16x2* xv = (const f16x2*)g1s + 10 * qq;
    if (jq < 75){
#pragma unroll
      for (int p = 0; p < 10; p++) a = fdot2v(gW2s[jq * 40 + 10 * qq + p], xv[p], a);
    }
    a += __shfl_xor(a, 1); a += __shfl_xor(a, 2);
    if (lv) g2s[jq] = (f16)leaky_f(a + gb2v);
  }
  __syncthreads();
  if (tid < 2){
    const f16x2* g2v = (const f16x2*)g2s;
    float a = gb3[tid];
    for (int p = 0; p < 40; p++) a = fdot2v(gW3s[tid * 40 + p], g2v[p], a);
    gx_ws[b * 2 + tid] = a;
  }
}

// ===================== Kernel 2: z0 + forecast ODE + decoder =====================
__global__ __launch_bounds__(512, 2) void k_forecast(
    const float* __restrict__ t_future, const float* __restrict__ eps,
    const float* __restrict__ fW1, const float* __restrict__ fb1,
    const float* __restrict__ fW2, const float* __restrict__ fb2,
    const float* __restrict__ fW3, const float* __restrict__ fb3,
    const float* __restrict__ oW1, const float* __restrict__ ob1,
    const float* __restrict__ oW2, const float* __restrict__ ob2,
    const float* __restrict__ oW3, const float* __restrict__ ob3,
    const float* __restrict__ gx_ws, float* __restrict__ out)
{
  __shared__ f16x8 ustV[16];
  __shared__ f16x8 ystV[16];
  __shared__ f16x8 x1V[36];
  __shared__ f16x8 x2V[36];
  __shared__ f16x8 o1V[12];      // 96 f16, pads zero
  __shared__ f16x8 o2V[12];
  __shared__ float trow_lds[256];   // t_future row (VMEM-free loop)
  __shared__ float out_lds[256];    // decoder outputs (bulk store at end)

  const int tid = threadIdx.x;
  const int b = blockIdx.x;
  f16* ust = (f16*)ustV;
  f16* yst = (f16*)ystV;
  f16* x1s = (f16*)x1V;
  f16* x2s = (f16*)x2V;
  f16* o1s = (f16*)o1V;
  f16* o2s = (f16*)o2V;

  FRM R;
  load_field_mfma(R, tid, fW1, fb1, fW2, fb2, fW3, fb3);

  // Decoder weights in registers
  const int jq = tid >> 2, qq = tid & 3;
  const bool dv = jq < 75;
  const bool lv = (qq == 0 && dv);
  DEC dc;
  ld_pairs<16>(oW1, dv ? jq : 0, 100, 32 * qq, dc.dW1, dv);
  ld_pairs<12>(oW2, dv ? jq : 0, 75, 24 * qq, dc.dW2, dv);
  {
    int t2 = tid - 384;                 // out-stage home: wave 6
    bool v = (t2 >= 0 && t2 < 40);
    ld_pairs<1>(oW3, 0, 75, v ? 2 * t2 : 0, &dc.dW3, v);
  }
  dc.ob1v = lv ? ob1[jq] : 0.f;
  dc.ob2v = lv ? ob2[jq] : 0.f;
  dc.ob3v = ob3[0];

  for (int i = tid; i < 128; i += 512){ ust[i] = (f16)0.f; yst[i] = (f16)0.f; }
  for (int i = tid; i < 288; i += 512){ x1s[i] = (f16)0.f; x2s[i] = (f16)0.f; }
  for (int i = tid; i < 96;  i += 512){ o1s[i] = (f16)0.f; o2s[i] = (f16)0.f; }
  if (tid < 256) trow_lds[tid] = t_future[b * 256 + tid];

  const int lm = tid & 15, lg2 = (tid >> 4) & 3, wv = tid >> 6;
  bool wr3; int row3;
  if (wv < 6)      { wr3 = (lm < 4);  row3 = 16 * wv + 4 * lg2 + (lm & 3); }
  else if (wv == 7){ wr3 = (lm == 0); row3 = 96 + lg2; }
  else             { wr3 = false;     row3 = 0; }
  float k1v = 0.f, k2v = 0.f, k3v = 0.f, yfr = 0.f;

  auto kval = [&](f32x4 a){
    float av = (wv == 7) ? a.x : sel4(a, lm);
    return tanh_f(av + R.b3w);
  };

  // z0 = loc + scale * eps  (pr reshuffle across rows via gx_ws)
  if (wr3){
    float loc, scl;
    if (b < 128){ loc = gx_ws[4 * b];              scl = gx_ws[4 * b + 2]; }
    else        { loc = fabsf(gx_ws[4 * b - 511]); scl = fabsf(gx_ws[4 * b - 509]); }
    float e = eps[row3 * 256 + b];
    yfr = loc + scl * e;
    yst[row3] = (f16)yfr; ust[1 + row3] = (f16)yfr;
  }
  __syncthreads();

  float tc_carry = trow_lds[0];
#pragma unroll 1
  for (int iv = 0; iv < 255; iv++){
    float tp = tc_carry;
    float tc = trow_lds[iv + 1];
    tc_carry = tc;
    float dts = (tc - tp) * 0.5f;
#pragma unroll 1
    for (int sub = 0; sub < 2; sub++){
      float t0 = tp + sub * dts;
      __syncthreads();
      f32x4 a;
      if (sub == 0)   // fold decode(iv): yst holds y from before this interval
        a = field_eval_m<true >(R, dc, t0, tid, ust, x1s, x2s,
                                (const f16x8*)yst, o1s, o2s, out_lds, iv);
      else
        a = field_eval_m<false>(R, dc, t0, tid, ust, x1s, x2s,
                                nullptr, nullptr, nullptr, nullptr, 0);
      if (wr3){ float kv = kval(a); k1v = kv;
                ust[1 + row3] = (f16)(yfr + 0.5f * dts * kv); }
      __syncthreads();
      a = field_eval_m<false>(R, dc, t0 + 0.5f * dts, tid, ust, x1s, x2s,
                              nullptr, nullptr, nullptr, nullptr, 0);
      if (wr3){ float kv = kval(a); k2v = kv;
                ust[1 + row3] = (f16)(yfr + 0.5f * dts * kv); }
      __syncthreads();
      a = field_eval_m<false>(R, dc, t0 + 0.5f * dts, tid, ust, x1s, x2s,
                              nullptr, nullptr, nullptr, nullptr, 0);
      if (wr3){ float kv = kval(a); k3v = kv;
                ust[1 + row3] = (f16)(yfr + dts * kv); }
      __syncthreads();
      a = field_eval_m<false>(R, dc, t0 + dts, tid, ust, x1s, x2s,
                              nullptr, nullptr, nullptr, nullptr, 0);
      if (wr3){
        float kv = kval(a);
        float yn = yfr + dts * (k1v + 2.f * (k2v + k3v) + kv) * (1.f / 6.f);
        yfr = yn; ust[1 + row3] = (f16)yn; yst[row3] = (f16)yn;
      }
    }
  }

  // ---- epilogue: decode(255) ----
  __syncthreads();
  if (dv){
    float a = dot_chunks<4>(dc.dW1, (const f16x8*)yst, 4 * qq);
    a += __shfl_xor(a, 1); a += __shfl_xor(a, 2);
    if (qq == 0) o1s[jq] = (f16)leaky_f(a + dc.ob1v);
  }
  __syncthreads();
  if (dv){
    float a = dot_chunks<3>(dc.dW2, (const f16x8*)o1s, 3 * qq);
    a += __shfl_xor(a, 1); a += __shfl_xor(a, 2);
    if (qq == 0) o2s[jq] = (f16)leaky_f(a + dc.ob2v);
  }
  __syncthreads();
  if (wv == 6){
    int t2 = tid - 384;
    float a = 0.f;
    if (t2 < 40) a = fdot2v(dc.dW3, ((const f16x2*)o2s)[t2], 0.f);
    a += __shfl_xor(a, 1);  a += __shfl_xor(a, 2);  a += __shfl_xor(a, 4);
    a += __shfl_xor(a, 8);  a += __shfl_xor(a, 16); a += __shfl_xor(a, 32);
    if (t2 == 0) out_lds[255] = a + dc.ob3v;
  }
  // ---- bulk store of all 256 outputs ----
  __syncthreads();
  if (tid < 256) out[b * 256 + tid] = out_lds[tid];
}

extern "C" void kernel_launch(void* const* d_in, const int* in_sizes, int n_in,
                              void* d_out, int out_size, void* d_ws, size_t ws_size,
                              hipStream_t stream) {
  (void)in_sizes; (void)n_in; (void)out_size; (void)ws_size;
  const float* past     = (const float*)d_in[0];
  const float* h0       = (const float*)d_in[1];
  const float* t_future = (const float*)d_in[2];
  const float* eps      = (const float*)d_in[3];
  const float* fW1 = (const float*)d_in[4];  const float* fb1 = (const float*)d_in[5];
  const float* fW2 = (const float*)d_in[6];  const float* fb2 = (const float*)d_in[7];
  const float* fW3 = (const float*)d_in[8];  const float* fb3 = (const float*)d_in[9];
  const float* Wih = (const float*)d_in[10]; const float* Whh = (const float*)d_in[11];
  const float* bih = (const float*)d_in[12]; const float* bhh = (const float*)d_in[13];
  const float* gW1 = (const float*)d_in[14]; const float* gb1 = (const float*)d_in[15];
  const float* gW2 = (const float*)d_in[16]; const float* gb2 = (const float*)d_in[17];
  const float* gW3 = (const float*)d_in[18]; const float* gb3 = (const float*)d_in[19];
  const float* oW1 = (const float*)d_in[20]; const float* ob1 = (const float*)d_in[21];
  const float* oW2 = (const float*)d_in[22]; const float* ob2 = (const float*)d_in[23];
  const float* oW3 = (const float*)d_in[24]; const float* ob3 = (const float*)d_in[25];
  float* gxws = (float*)d_ws;
  float* out = (float*)d_out;

  hipLaunchKernelGGL(k_encode, dim3(256), dim3(512), 0, stream,
      past, h0, fW1, fb1, fW2, fb2, fW3, fb3,
      Wih, Whh, bih, bhh, gW1, gb1, gW2, gb2, gW3, gb3, gxws);
  hipLaunchKernelGGL(k_forecast, dim3(256), dim3(512), 0, stream,
      t_future, eps, fW1, fb1, fW2, fb2, fW3, fb3,
      oW1, ob1, oW2, ob2, oW3, ob3, gxws, out);
}

// Round 9
// 3485.724 us; speedup vs baseline: 1.0214x; 1.0214x over previous
//
#include <hip/hip_runtime.h>
#include <hip/hip_fp16.h>

typedef _Float16 f16;
typedef _Float16 f16x2 __attribute__((ext_vector_type(2)));
typedef _Float16 f16x8 __attribute__((ext_vector_type(8)));
typedef float f32x4 __attribute__((ext_vector_type(4)));

__device__ __forceinline__ float fdot2v(f16x2 a, f16x2 b, float c){
#if __has_builtin(__builtin_amdgcn_fdot2)
  return __builtin_amdgcn_fdot2(a, b, c, false);
#else
  return c + (float)a.x * (float)b.x + (float)a.y * (float)b.y;
#endif
}

__device__ __forceinline__ float rcp_f(float x){
#if __has_builtin(__builtin_amdgcn_rcpf)
  return __builtin_amdgcn_rcpf(x);
#else
  return 1.f / x;
#endif
}

__device__ __forceinline__ float tanh_f(float x){
  return 1.f - 2.f * rcp_f(__expf(2.f * x) + 1.f);
}
__device__ __forceinline__ float sigm_f(float x){
  return rcp_f(1.f + __expf(-x));
}
__device__ __forceinline__ float leaky_f(float x){
  return x >= 0.f ? x : x * (1.0f / 5.5f);
}

// Load NP f32 pairs from row-major W[row][c0 + 2p (+1)] into f16x2 regs,
// zero-padding out-of-range columns. Row forced safe by caller when !valid.
template<int NP>
__device__ __forceinline__ void ld_pairs(const float* W, int row, int ncols, int c0,
                                         f16x2* dst, bool valid){
  const float* base = W + (long)row * ncols;
#pragma unroll
  for (int p = 0; p < NP; p++){
    int c = c0 + 2 * p;
    f16x2 v;
    v.x = (valid && c     < ncols) ? (f16)base[c]     : (f16)0.f;
    v.y = (valid && c + 1 < ncols) ? (f16)base[c + 1] : (f16)0.f;
    dst[p] = v;
  }
}

// Dot of NCH f16x8 LDS chunks against register weights w[4*NCH] (f16x2).
template<int NCH>
__device__ __forceinline__ float dot_chunks(const f16x2* w, const f16x8* x, int chunk0){
  float a0 = 0.f, a1 = 0.f, a2 = 0.f, a3 = 0.f;
#pragma unroll
  for (int c = 0; c < NCH; c++){
    union { f16x8 v; f16x2 h[4]; } u;
    u.v = x[chunk0 + c];
    a0 = fdot2v(w[4*c + 0], u.h[0], a0);
    a1 = fdot2v(w[4*c + 1], u.h[1], a1);
    a2 = fdot2v(w[4*c + 2], u.h[2], a2);
    a3 = fdot2v(w[4*c + 3], u.h[3], a3);
  }
  return (a0 + a1) + (a2 + a3);
}

// Build one MFMA A-fragment: 8 f16 along K for this lane's row.
// 16x16x32_f16 layout: row m = lane&15, k = 8*(lane>>4) + j (j = 0..7).
__device__ __forceinline__ f16x8 ldfrag(const float* W, int row, int ncols, int k0, bool valid){
  f16x8 v;
#pragma unroll
  for (int j = 0; j < 8; j++){
    int c = k0 + j;
    v[j] = (valid && c < ncols) ? (f16)W[(long)row * ncols + c] : (f16)0.f;
  }
  return v;
}

__device__ __forceinline__ float sel4(f32x4 a, int c){
  float v = a.x;
  v = (c == 1) ? a.y : v;
  v = (c == 2) ? a.z : v;
  v = (c == 3) ? a.w : v;
  return v;
}

#define MFMA16(A,B,C) __builtin_amdgcn_mfma_f32_16x16x32_f16((A),(B),(C),0,0,0)

// Field MLP as MFMA, 18 tiles of 16 rows for stages 1/2 (N=275 padded to 288;
// rows >=275 produce finite garbage multiplied by zero-padded weights downstream).
// Wave wv owns tiles {2wv, 2wv+1}; waves 6,7 additionally own tiles 16,17
// (rows 256..287) via the af[] overlay. Stage 3 (N=100): waves 0..5 own tiles
// 0..5 (rows 0..95) via af[]; rows 96..99 are a 16-way fdot2 tail on wave 7.
// Stage-1 input u: u[0]=0 (t applied as fp32 scalar), u[1+i]=y[i], padded to 128.
struct FRM {
  f16x8 a1[2][4];   // fW1 fragments, K = 128
  f16x8 a2[2][9];   // fW2 fragments, K = 288
  f16x8 af[13];     // wv<6: [0..8] = fW3 frags; wv>=6: [0..3] = fW1 tile16/17, [4..12] = fW2 tile16/17
  f16x2 w3b[9];     // wave 7: stage-3 tail rows 96..99, cols 18*lm..18*lm+17
  float w1tw, b1w, b2w;   // writer-lane (lm<12) consts
  float b3w;
};

// Decoder register context (k_forecast only; DCE'd when unused).
struct DEC {
  f16x2 dW1[16]; f16x2 dW2[12]; f16x2 dW3;
  float ob1v, ob2v, ob3v;
};

__device__ __forceinline__ void load_field_mfma(FRM& R, int tid,
    const float* fW1, const float* fb1, const float* fW2, const float* fb2,
    const float* fW3, const float* fb3)
{
  const int lane = tid & 63, wv = tid >> 6;
  const int lm = lane & 15, lg = lane >> 4;
  const int r0 = 32 * wv + lm, r1 = r0 + 16;      // rows of tiles 2wv, 2wv+1 (<= 255)
#pragma unroll
  for (int c = 0; c < 4; c++){
    R.a1[0][c] = ldfrag(fW1, r0, 101, 32 * c + 8 * lg, true);
    R.a1[1][c] = ldfrag(fW1, r1, 101, 32 * c + 8 * lg, true);
  }
#pragma unroll
  for (int c = 0; c < 9; c++){
    R.a2[0][c] = ldfrag(fW2, r0, 275, 32 * c + 8 * lg, true);
    R.a2[1][c] = ldfrag(fW2, r1, 275, 32 * c + 8 * lg, true);
  }
  if (wv < 6){
    const int r3 = 16 * wv + lm;                  // <= 95, always valid
#pragma unroll
    for (int c = 0; c < 9; c++)
      R.af[c] = ldfrag(fW3, r3, 275, 32 * c + 8 * lg, true);
#pragma unroll
    for (int c = 9; c < 13; c++) R.af[c] = (f16x8)(f16)0.f;
  } else {
    const int r2 = 256 + 16 * (wv - 6) + lm;      // tiles 16/17: rows 256..287
    const bool v2 = r2 < 275;
    const int r2c = v2 ? r2 : 0;
#pragma unroll
    for (int c = 0; c < 4; c++)
      R.af[c] = ldfrag(fW1, r2c, 101, 32 * c + 8 * lg, v2);
#pragma unroll
    for (int c = 0; c < 9; c++)
      R.af[4 + c] = ldfrag(fW2, r2c, 275, 32 * c + 8 * lg, v2);
  }
  // wave-7 stage-3 tail: rows 96+lg, 16-way K split over cols 18*lm..
  {
    const bool w7 = (wv == 7);
    ld_pairs<9>(fW3, w7 ? (96 + lg) : 0, 275, 18 * lm, R.w3b, w7);
  }
  // writer-lane consts (lm<12): s = lm>>2 selects tile {2wv, 2wv+1, extra}
  {
    const int s = lm >> 2;
    const bool use3 = (s == 2) && (wv >= 6);
    int rw = use3 ? (256 + 16 * (wv - 6) + 4 * lg + (lm & 3))
                  : (32 * wv + 16 * (s & 1) + 4 * lg + (lm & 3));
    int rwc = rw < 275 ? rw : 274;
    R.w1tw = fW1[rwc * 101];
    R.b1w  = fb1[rwc];
    R.b2w  = fb2[rwc];
  }
  if (wv < 6)       R.b3w = fb3[16 * wv + 4 * lg + (lm & 3)];   // rows <96
  else if (wv == 7) R.b3w = fb3[96 + lg];
  else              R.b3w = 0.f;
}

// One field evaluation via MFMA. ust: 128 f16 [0, y0..y99, 0...].
// x1s/x2s: 288 f16. 2 internal barriers. Returns stage-3 result:
// waves 0..5: f32x4 acc (rows 16wv+4lg+reg); wave 7: reduced tail value in .x
// (rows 96+lg on lm==0 lanes). Caller applies tanh + b3w on writer lanes.
// D=true folds one decoder evaluation (yv -> o1 -> o2 -> outp[tf]);
// out-stage runs on wave 6 (idle in stage 3).
template<bool D>
__device__ __forceinline__ f32x4 field_eval_m(const FRM& R, const DEC& dc,
    float t, int tid, f16* ust, f16* x1s, f16* x2s,
    const f16x8* yv, f16* o1s, f16* o2s, float* outp, int tf)
{
  const int lm = tid & 15, lg = (tid >> 4) & 3, wv = tid >> 6;
  const bool x3 = (wv >= 6);
  const int nw = x3 ? 12 : 8;
  const f16x8* ub  = (const f16x8*)ust;
  const f16x8* x1b = (const f16x8*)x1s;
  const f16x8* x2b = (const f16x8*)x2s;
  const f32x4 zz = {0.f, 0.f, 0.f, 0.f};

  // ---- stage 1: x1 = tanh([t,y] @ fW1^T + fb1), 18 tiles MFMA ----
  {
    f16x8 u0 = ub[lg], u1 = ub[4 + lg], u2 = ub[8 + lg], u3 = ub[12 + lg];
    f32x4 A0 = zz, A1 = zz, A2 = zz, B0 = zz, B1 = zz, B2 = zz;
    __builtin_amdgcn_s_setprio(1);
    A0 = MFMA16(R.a1[0][0], u0, A0);  A1 = MFMA16(R.a1[1][0], u0, A1);
    B0 = MFMA16(R.a1[0][1], u1, B0);  B1 = MFMA16(R.a1[1][1], u1, B1);
    A0 = MFMA16(R.a1[0][2], u2, A0);  A1 = MFMA16(R.a1[1][2], u2, A1);
    B0 = MFMA16(R.a1[0][3], u3, B0);  B1 = MFMA16(R.a1[1][3], u3, B1);
    if (x3){
      A2 = MFMA16(R.af[0], u0, A2);  B2 = MFMA16(R.af[1], u1, B2);
      A2 = MFMA16(R.af[2], u2, A2);  B2 = MFMA16(R.af[3], u3, B2);
    }
    __builtin_amdgcn_s_setprio(0);
    if (D){                              // decoder stage 1 rides along
      int jq = tid >> 2, qq = tid & 3;
      if (jq < 75){
        float a = dot_chunks<4>(dc.dW1, yv, 4 * qq);
        a += __shfl_xor(a, 1); a += __shfl_xor(a, 2);
        if (qq == 0) o1s[jq] = (f16)leaky_f(a + dc.ob1v);
      }
    }
    if (lm < nw){
      int s = lm >> 2, reg = lm & 3;
      int rw = (s == 2) ? (256 + 16 * (wv - 6) + 4 * lg + reg)
                        : (32 * wv + 16 * s + 4 * lg + reg);
      float v0 = sel4(A0 + B0, reg), v1 = sel4(A1 + B1, reg), v2 = sel4(A2 + B2, reg);
      float v = (s == 0) ? v0 : ((s == 1) ? v1 : v2);
      x1s[rw] = (f16)tanh_f(v + R.w1tw * t + R.b1w);
    }
  }
  __syncthreads();

  // ---- stage 2: x2 = tanh(x1 @ fW2^T + fb2), 18 tiles MFMA ----
  {
    f32x4 A0 = zz, A1 = zz, A2 = zz, B0 = zz, B1 = zz, B2 = zz;
    __builtin_amdgcn_s_setprio(1);
#pragma unroll
    for (int c = 0; c < 5; c++){
      f16x8 bp = x1b[4 * c + lg];
      A0 = MFMA16(R.a2[0][c], bp, A0);
      A1 = MFMA16(R.a2[1][c], bp, A1);
      if (x3) A2 = MFMA16(R.af[4 + c], bp, A2);
    }
#pragma unroll
    for (int c = 5; c < 9; c++){
      f16x8 bq = x1b[4 * c + lg];
      B0 = MFMA16(R.a2[0][c], bq, B0);
      B1 = MFMA16(R.a2[1][c], bq, B1);
      if (x3) B2 = MFMA16(R.af[4 + c], bq, B2);
    }
    __builtin_amdgcn_s_setprio(0);
    if (D){                              // decoder stage 2
      int jq = tid >> 2, qq = tid & 3;
      if (jq < 75){
        float a = dot_chunks<3>(dc.dW2, (const f16x8*)o1s, 3 * qq);
        a += __shfl_xor(a, 1); a += __shfl_xor(a, 2);
        if (qq == 0) o2s[jq] = (f16)leaky_f(a + dc.ob2v);
      }
    }
    if (lm < nw){
      int s = lm >> 2, reg = lm & 3;
      int rw = (s == 2) ? (256 + 16 * (wv - 6) + 4 * lg + reg)
                        : (32 * wv + 16 * s + 4 * lg + reg);
      float v0 = sel4(A0 + B0, reg), v1 = sel4(A1 + B1, reg), v2 = sel4(A2 + B2, reg);
      float v = (s == 0) ? v0 : ((s == 1) ? v1 : v2);
      x2s[rw] = (f16)tanh_f(v + R.b2w);
    }
  }
  __syncthreads();

  // ---- stage 3: f = tanh(x2 @ fW3^T + fb3) ----
  f32x4 acc3 = zz;
  if (wv < 6){                           // rows 0..95 via MFMA
    f32x4 r0 = zz, r1 = zz;
    __builtin_amdgcn_s_setprio(1);
#pragma unroll
    for (int c = 0; c < 5; c++) r0 = MFMA16(R.af[c], x2b[4 * c + lg], r0);
#pragma unroll
    for (int c = 5; c < 9; c++) r1 = MFMA16(R.af[c], x2b[4 * c + lg], r1);
    __builtin_amdgcn_s_setprio(0);
    acc3 = r0 + r1;
  } else if (wv == 7){                   // rows 96..99, 16-way fdot2 tail
    float a2t = 0.f;
    const f16x2* xv2 = (const f16x2*)x2s + 9 * lm;
#pragma unroll
    for (int p = 0; p < 9; p++) a2t = fdot2v(R.w3b[p], xv2[p], a2t);
    a2t += __shfl_xor(a2t, 1); a2t += __shfl_xor(a2t, 2);
    a2t += __shfl_xor(a2t, 4); a2t += __shfl_xor(a2t, 8);
    acc3.x = a2t;
  }
  if (D){                                // decoder out-stage on wave 6
    if (wv == 6){
      int t2 = tid - 384;
      float a = 0.f;
      if (t2 < 40) a = fdot2v(dc.dW3, ((const f16x2*)o2s)[t2], 0.f);
      a += __shfl_xor(a, 1);  a += __shfl_xor(a, 2);  a += __shfl_xor(a, 4);
      a += __shfl_xor(a, 8);  a += __shfl_xor(a, 16); a += __shfl_xor(a, 32);
      if (t2 == 0) outp[tf] = a + dc.ob3v;
    }
  }
  return acc3;
}

// ===================== Kernel 1: encoder + latent MLP =====================
__global__ __launch_bounds__(512, 2) void k_encode(
    const float* __restrict__ past, const float* __restrict__ h0,
    const float* __restrict__ fW1, const float* __restrict__ fb1,
    const float* __restrict__ fW2, const float* __restrict__ fb2,
    const float* __restrict__ fW3, const float* __restrict__ fb3,
    const float* __restrict__ Wih, const float* __restrict__ Whh,
    const float* __restrict__ bih, const float* __restrict__ bhh,
    const float* __restrict__ gW1, const float* __restrict__ gb1,
    const float* __restrict__ gW2, const float* __restrict__ gb2,
    const float* __restrict__ gW3, const float* __restrict__ gb3,
    float* __restrict__ gx_ws)
{
  __shared__ f16x8 ustV[16];     // [0, y, 0..] staged for stage-1 MFMA
  __shared__ f16x8 ystV[16];     // y-only staged (GRU / latent MLP)
  __shared__ f16x8 x1V[36];      // 288 f16
  __shared__ f16x8 x2V[36];
  __shared__ float yf[100];      // fp32 master state
  __shared__ float ghs[300];
  __shared__ f16x2 gW1s[75 * 52];
  __shared__ f16x2 gW2s[75 * 40];
  __shared__ f16x2 gW3s[80];
  __shared__ f16x2 g1s2[40];
  __shared__ f16x2 g2s2[40];

  const int tid = threadIdx.x;
  const int b = blockIdx.x;
  f16* ust = (f16*)ustV;
  f16* yst = (f16*)ystV;
  f16* x1s = (f16*)x1V;
  f16* x2s = (f16*)x2V;
  f16* g1s = (f16*)g1s2;
  f16* g2s = (f16*)g2s2;

  FRM R;
  load_field_mfma(R, tid, fW1, fb1, fW2, fb2, fW3, fb3);
  DEC dcz{};   // unused (D=false); DCE'd

  // GRU hidden-hidden: pass1 rows 0..255 (2-way chunked), pass2 rows 256..299 (8-way)
  f16x2 whh[28]; float bhhv;
  f16x2 whhb[7]; float bhhbv;
  {
    int j1 = tid >> 1, h = tid & 1;
    ld_pairs<28>(Whh, j1, 100, 56 * h, whh, true);
    bhhv = bhh[j1];
    bool p2 = tid < 352;
    int j2 = 256 + (tid >> 3), s7 = tid & 7;
    ld_pairs<7>(Whh, p2 ? j2 : 0, 100, 14 * s7, whhb, p2);
    bhhbv = p2 ? bhh[j2] : 0.f;
  }
  float wihr=0,wihz=0,wihn=0,bihr=0,bihz=0,bihn=0;
  if (tid < 100){
    wihr = Wih[tid];       bihr = bih[tid];
    wihz = Wih[tid + 100]; bihz = bih[tid + 100];
    wihn = Wih[tid + 200]; bihn = bih[tid + 200];
  }
  const int jq = tid >> 2, qq = tid & 3;
  const bool lv = (qq == 0 && jq < 75);
  float gb1v = lv ? gb1[jq] : 0.f;
  float gb2v = lv ? gb2[jq] : 0.f;

  // latent weights -> LDS (f16, padded strides; used once)
  for (int i = tid; i < 75 * 52; i += 512){
    int r = i / 52, c = 2 * (i % 52);
    f16x2 v;
    v.x = (c     < 100) ? (f16)gW1[r * 100 + c]     : (f16)0.f;
    v.y = (c + 1 < 100) ? (f16)gW1[r * 100 + c + 1] : (f16)0.f;
    gW1s[i] = v;
  }
  for (int i = tid; i < 75 * 40; i += 512){
    int r = i / 40, c = 2 * (i % 40);
    f16x2 v;
    v.x = (c     < 75) ? (f16)gW2[r * 75 + c]     : (f16)0.f;
    v.y = (c + 1 < 75) ? (f16)gW2[r * 75 + c + 1] : (f16)0.f;
    gW2s[i] = v;
  }
  for (int i = tid; i < 80; i += 512){
    int r = i / 40, c = 2 * (i % 40);
    f16x2 v;
    v.x = (c     < 75) ? (f16)gW3[r * 75 + c]     : (f16)0.f;
    v.y = (c + 1 < 75) ? (f16)gW3[r * 75 + c + 1] : (f16)0.f;
    gW3s[i] = v;
  }
  // staging init (ust[0] stays 0 forever; ust pads 101..127 stay 0)
  for (int i = tid; i < 128; i += 512){ ust[i] = (f16)0.f; yst[i] = (f16)0.f; }
  for (int i = tid; i < 288; i += 512){ x1s[i] = (f16)0.f; x2s[i] = (f16)0.f; }
  for (int i = tid; i < 80;  i += 512){ g1s[i] = (f16)0.f; g2s[i] = (f16)0.f; }
  if (tid < 100){
    float v = h0[b * 100 + tid];
    yf[tid] = v; yst[tid] = (f16)v; ust[1 + tid] = (f16)v;
  }
  __syncthreads();

  const int lm = tid & 15, lg2 = (tid >> 4) & 3, wv = tid >> 6;
  bool wr3; int row3;
  if (wv < 6)      { wr3 = (lm < 4);  row3 = 16 * wv + 4 * lg2 + (lm & 3); }
  else if (wv == 7){ wr3 = (lm == 0); row3 = 96 + lg2; }
  else             { wr3 = false;     row3 = 0; }
  float k1v = 0.f, k2v = 0.f, k3v = 0.f;

  auto kval = [&](f32x4 a){
    float av = (wv == 7) ? a.x : sel4(a, lm);
    return tanh_f(av + R.b3w);
  };

  auto rk_interval = [&](float tp, float tc){
    float dts = (tc - tp) * 0.5f;   // (t1-t0)/NSUB
#pragma unroll 1
    for (int sub = 0; sub < 2; sub++){
      float t0 = tp + sub * dts;
      float yfr = 0.f;
      __syncthreads();
      if (wr3) yfr = yf[row3];       // refresh after GRU / previous substep
      f32x4 a = field_eval_m<false>(R, dcz, t0, tid, ust, x1s, x2s,
                                    nullptr, nullptr, nullptr, nullptr, 0);
      if (wr3){ float kv = kval(a); k1v = kv;
                ust[1 + row3] = (f16)(yfr + 0.5f * dts * kv); }
      __syncthreads();
      a = field_eval_m<false>(R, dcz, t0 + 0.5f * dts, tid, ust, x1s, x2s,
                              nullptr, nullptr, nullptr, nullptr, 0);
      if (wr3){ float kv = kval(a); k2v = kv;
                ust[1 + row3] = (f16)(yfr + 0.5f * dts * kv); }
      __syncthreads();
      a = field_eval_m<false>(R, dcz, t0 + 0.5f * dts, tid, ust, x1s, x2s,
                              nullptr, nullptr, nullptr, nullptr, 0);
      if (wr3){ float kv = kval(a); k3v = kv;
                ust[1 + row3] = (f16)(yfr + dts * kv); }
      __syncthreads();
      a = field_eval_m<false>(R, dcz, t0 + dts, tid, ust, x1s, x2s,
                              nullptr, nullptr, nullptr, nullptr, 0);
      if (wr3){
        float kv = kval(a);
        float yn = yfr + dts * (k1v + 2.f * (k2v + k3v) + kv) * (1.f / 6.f);
        yf[row3] = yn; ust[1 + row3] = (f16)yn; yst[row3] = (f16)yn;
      }
    }
  };

  const float* prow = past + b * 64;  // (32 steps) x [t, x]
  float tprev = 0.f;
#pragma unroll 1
  for (int st = 0; st < 32; st++){
    float tc = prow[2 * st];
    float tp = (st == 0) ? (tc - 1.f) : tprev;
    tprev = tc;
    rk_interval(tp, tc);
    // ---- GRU update ----
    __syncthreads();   // yst = integrated h ready
    {
      int j1 = tid >> 1, h = tid & 1;
      float a = dot_chunks<7>(whh, ystV, 7 * h);
      a += __shfl_xor(a, 1);
      if (!h) ghs[j1] = a + bhhv;
      if (tid < 352){
        int s7 = tid & 7;
        float a2 = 0.f;
        const f16x2* yv2 = (const f16x2*)ystV + 7 * s7;
#pragma unroll
        for (int p = 0; p < 7; p++) a2 = fdot2v(whhb[p], yv2[p], a2);
        a2 += __shfl_xor(a2, 1); a2 += __shfl_xor(a2, 2); a2 += __shfl_xor(a2, 4);
        if (s7 == 0) ghs[256 + (tid >> 3)] = a2 + bhhbv;
      }
    }
    __syncthreads();
    if (tid < 100){
      float x = prow[2 * st + 1];
      float r = sigm_f(x * wihr + bihr + ghs[tid]);
      float z = sigm_f(x * wihz + bihz + ghs[tid + 100]);
      float n = tanh_f(x * wihn + bihn + r * ghs[tid + 200]);
      float hn = (1.f - z) * n + z * yf[tid];
      yf[tid] = hn; yst[tid] = (f16)hn; ust[1 + tid] = (f16)hn;
    }
  }

  // ---- latent MLP: gx = (leaky,leaky,linear)(h) ----
  __syncthreads();
  {
    float a = 0.f;
    const f16x2* yv = (const f16x2*)ystV + 13 * qq;
    if (jq < 75){
#pragma unroll
      for (int p = 0; p < 13; p++) a = fdot2v(gW1s[jq * 52 + 13 * qq + p], yv[p], a);
    }
    a += __shfl_xor(a, 1); a += __shfl_xor(a, 2);
    if (lv) g1s[jq] = (f16)leaky_f(a + gb1v);
  }
  __syncthreads();
  {
    float a = 0.f;
    const f16x2* xv = (const f16x2*)g1s + 10 * qq;
    if (jq < 75){
#pragma unroll
      for (int p = 0; p < 10; p++) a = fdot2v(gW2s[jq * 40 + 10 * qq + p], xv[p], a);
    }
    a += __shfl_xor(a, 1); a += __shfl_xor(a, 2);
    if (lv) g2s[jq] = (f16)leaky_f(a + gb2v);
  }
  __syncthreads();
  if (tid < 2){
    const f16x2* g2v = (const f16x2*)g2s;
    float a = gb3[tid];
    for (int p = 0; p < 40; p++) a = fdot2v(gW3s[tid * 40 + p], g2v[p], a);
    gx_ws[b * 2 + tid] = a;
  }
}

// ===================== Kernel 2: z0 + forecast ODE + decoder =====================
__global__ __launch_bounds__(512, 2) void k_forecast(
    const float* __restrict__ t_future, const float* __restrict__ eps,
    const float* __restrict__ fW1, const float* __restrict__ fb1,
    const float* __restrict__ fW2, const float* __restrict__ fb2,
    const float* __restrict__ fW3, const float* __restrict__ fb3,
    const float* __restrict__ oW1, const float* __restrict__ ob1,
    const float* __restrict__ oW2, const float* __restrict__ ob2,
    const float* __restrict__ oW3, const float* __restrict__ ob3,
    const float* __restrict__ gx_ws, float* __restrict__ out)
{
  __shared__ f16x8 ustV[16];
  __shared__ f16x8 ystV[16];
  __shared__ f16x8 x1V[36];
  __shared__ f16x8 x2V[36];
  __shared__ f16x8 o1V[12];      // 96 f16, pads zero
  __shared__ f16x8 o2V[12];

  const int tid = threadIdx.x;
  const int b = blockIdx.x;
  f16* ust = (f16*)ustV;
  f16* yst = (f16*)ystV;
  f16* x1s = (f16*)x1V;
  f16* x2s = (f16*)x2V;
  f16* o1s = (f16*)o1V;
  f16* o2s = (f16*)o2V;
  float* outb = out + b * 256;

  FRM R;
  load_field_mfma(R, tid, fW1, fb1, fW2, fb2, fW3, fb3);

  // Decoder weights in registers
  const int jq = tid >> 2, qq = tid & 3;
  const bool dv = jq < 75;
  const bool lv = (qq == 0 && dv);
  DEC dc;
  ld_pairs<16>(oW1, dv ? jq : 0, 100, 32 * qq, dc.dW1, dv);
  ld_pairs<12>(oW2, dv ? jq : 0, 75, 24 * qq, dc.dW2, dv);
  {
    int t2 = tid - 384;                 // out-stage home: wave 6
    bool v = (t2 >= 0 && t2 < 40);
    ld_pairs<1>(oW3, 0, 75, v ? 2 * t2 : 0, &dc.dW3, v);
  }
  dc.ob1v = lv ? ob1[jq] : 0.f;
  dc.ob2v = lv ? ob2[jq] : 0.f;
  dc.ob3v = ob3[0];

  for (int i = tid; i < 128; i += 512){ ust[i] = (f16)0.f; yst[i] = (f16)0.f; }
  for (int i = tid; i < 288; i += 512){ x1s[i] = (f16)0.f; x2s[i] = (f16)0.f; }
  for (int i = tid; i < 96;  i += 512){ o1s[i] = (f16)0.f; o2s[i] = (f16)0.f; }

  const int lm = tid & 15, lg2 = (tid >> 4) & 3, wv = tid >> 6;
  bool wr3; int row3;
  if (wv < 6)      { wr3 = (lm < 4);  row3 = 16 * wv + 4 * lg2 + (lm & 3); }
  else if (wv == 7){ wr3 = (lm == 0); row3 = 96 + lg2; }
  else             { wr3 = false;     row3 = 0; }
  float k1v = 0.f, k2v = 0.f, k3v = 0.f, yfr = 0.f;

  auto kval = [&](f32x4 a){
    float av = (wv == 7) ? a.x : sel4(a, lm);
    return tanh_f(av + R.b3w);
  };

  // z0 = loc + scale * eps  (pr reshuffle across rows via gx_ws)
  if (wr3){
    float loc, scl;
    if (b < 128){ loc = gx_ws[4 * b];              scl = gx_ws[4 * b + 2]; }
    else        { loc = fabsf(gx_ws[4 * b - 511]); scl = fabsf(gx_ws[4 * b - 509]); }
    float e = eps[row3 * 256 + b];
    yfr = loc + scl * e;
    yst[row3] = (f16)yfr; ust[1 + row3] = (f16)yfr;
  }
  __syncthreads();

  const float* trow = t_future + b * 256;
  float tc_carry = trow[0];
#pragma unroll 1
  for (int iv = 0; iv < 255; iv++){
    float tp = tc_carry;
    float tc = trow[iv + 1];
    tc_carry = tc;
    float dts = (tc - tp) * 0.5f;
#pragma unroll 1
    for (int sub = 0; sub < 2; sub++){
      float t0 = tp + sub * dts;
      __syncthreads();
      f32x4 a;
      if (sub == 0)   // fold decode(iv): yst holds y from before this interval
        a = field_eval_m<true >(R, dc, t0, tid, ust, x1s, x2s,
                                (const f16x8*)yst, o1s, o2s, outb, iv);
      else
        a = field_eval_m<false>(R, dc, t0, tid, ust, x1s, x2s,
                                nullptr, nullptr, nullptr, nullptr, 0);
      if (wr3){ float kv = kval(a); k1v = kv;
                ust[1 + row3] = (f16)(yfr + 0.5f * dts * kv); }
      __syncthreads();
      a = field_eval_m<false>(R, dc, t0 + 0.5f * dts, tid, ust, x1s, x2s,
                              nullptr, nullptr, nullptr, nullptr, 0);
      if (wr3){ float kv = kval(a); k2v = kv;
                ust[1 + row3] = (f16)(yfr + 0.5f * dts * kv); }
      __syncthreads();
      a = field_eval_m<false>(R, dc, t0 + 0.5f * dts, tid, ust, x1s, x2s,
                              nullptr, nullptr, nullptr, nullptr, 0);
      if (wr3){ float kv = kval(a); k3v = kv;
                ust[1 + row3] = (f16)(yfr + dts * kv); }
      __syncthreads();
      a = field_eval_m<false>(R, dc, t0 + dts, tid, ust, x1s, x2s,
                              nullptr, nullptr, nullptr, nullptr, 0);
      if (wr3){
        float kv = kval(a);
        float yn = yfr + dts * (k1v + 2.f * (k2v + k3v) + kv) * (1.f / 6.f);
        yfr = yn; ust[1 + row3] = (f16)yn; yst[row3] = (f16)yn;
      }
    }
  }

  // ---- epilogue: decode(255) ----
  __syncthreads();
  if (dv){
    float a = dot_chunks<4>(dc.dW1, (const f16x8*)yst, 4 * qq);
    a += __shfl_xor(a, 1); a += __shfl_xor(a, 2);
    if (qq == 0) o1s[jq] = (f16)leaky_f(a + dc.ob1v);
  }
  __syncthreads();
  if (dv){
    float a = dot_chunks<3>(dc.dW2, (const f16x8*)o1s, 3 * qq);
    a += __shfl_xor(a, 1); a += __shfl_xor(a, 2);
    if (qq == 0) o2s[jq] = (f16)leaky_f(a + dc.ob2v);
  }
  __syncthreads();
  if (wv == 6){
    int t2 = tid - 384;
    float a = 0.f;
    if (t2 < 40) a = fdot2v(dc.dW3, ((const f16x2*)o2s)[t2], 0.f);
    a += __shfl_xor(a, 1);  a += __shfl_xor(a, 2);  a += __shfl_xor(a, 4);
    a += __shfl_xor(a, 8);  a += __shfl_xor(a, 16); a += __shfl_xor(a, 32);
    if (t2 == 0) outb[255] = a + dc.ob3v;
  }
}

extern "C" void kernel_launch(void* const* d_in, const int* in_sizes, int n_in,
                              void* d_out, int out_size, void* d_ws, size_t ws_size,
                              hipStream_t stream) {
  (void)in_sizes; (void)n_in; (void)out_size; (void)ws_size;
  const float* past     = (const float*)d_in[0];
  const float* h0       = (const float*)d_in[1];
  const float* t_future = (const float*)d_in[2];
  const float* eps      = (const float*)d_in[3];
  const float* fW1 = (const float*)d_in[4];  const float* fb1 = (const float*)d_in[5];
  const float* fW2 = (const float*)d_in[6];  const float* fb2 = (const float*)d_in[7];
  const float* fW3 = (const float*)d_in[8];  const float* fb3 = (const float*)d_in[9];
  const float* Wih = (const float*)d_in[10]; const float* Whh = (const float*)d_in[11];
  const float* bih = (const float*)d_in[12]; const float* bhh = (const float*)d_in[13];
  const float* gW1 = (const float*)d_in[14]; const float* gb1 = (const float*)d_in[15];
  const float* gW2 = (const float*)d_in[16]; const float* gb2 = (const float*)d_in[17];
  const float* gW3 = (const float*)d_in[18]; const float* gb3 = (const float*)d_in[19];
  const float* oW1 = (const float*)d_in[20]; const float* ob1 = (const float*)d_in[21];
  const float* oW2 = (const float*)d_in[22]; const float* ob2 = (const float*)d_in[23];
  const float* oW3 = (const float*)d_in[24]; const float* ob3 = (const float*)d_in[25];
  float* gxws = (float*)d_ws;
  float* out = (float*)d_out;

  hipLaunchKernelGGL(k_encode, dim3(256), dim3(512), 0, stream,
      past, h0, fW1, fb1, fW2, fb2, fW3, fb3,
      Wih, Whh, bih, bhh, gW1, gb1, gW2, gb2, gW3, gb3, gxws);
  hipLaunchKernelGGL(k_forecast, dim3(256), dim3(512), 0, stream,
      t_future, eps, fW1, fb1, fW2, fb2, fW3, fb3,
      oW1, ob1, oW2, ob2, oW3, ob3, gxws, out);
}